// Round 8
// baseline (66.052 us; speedup 1.0000x reference)
//
#include <hip/hip_runtime.h>
#include <hip/hip_bf16.h>

#define BB 2
#define CC 320
#define HH 64
#define WW 128
#define MAXDISP 48
#define GG 40
#define CPG 8     // channels per group = C / G
#define CR 20     // C / R

typedef float fx4 __attribute__((ext_vector_type(4)));

// -------------------------------------------------------------------------
// Kernel 1: global average pool over H*W for each (img, b, c) row.
// 1280 blocks. Plain stores; visibility to the next kernel via the normal
// end-of-dispatch L2 flush (same-stream ordering) -- no atomics.
// -------------------------------------------------------------------------
__global__ __launch_bounds__(256) void gap_kernel(
    const float* __restrict__ ref, const float* __restrict__ tgt,
    float* __restrict__ gap /* [2][B][C] */) {
  int bid = blockIdx.x;            // 0 .. 1280
  int img = bid / (BB * CC);       // 0/1
  int rc  = bid - img * (BB * CC); // b*C + c
  const float* src = (img ? tgt : ref) + (size_t)rc * (HH * WW);
  const float4* v = reinterpret_cast<const float4*>(src);
  float acc = 0.f;
  for (int i = threadIdx.x; i < (HH * WW) / 4; i += 256) {
    float4 x = v[i];
    acc += (x.x + x.y) + (x.z + x.w);
  }
  for (int off = 32; off; off >>= 1) acc += __shfl_down(acc, off, 64);
  __shared__ float part[4];
  if ((threadIdx.x & 63) == 0) part[threadIdx.x >> 6] = acc;
  __syncthreads();
  if (threadIdx.x == 0) {
    float s = (part[0] + part[1]) + (part[2] + part[3]);
    gap[bid] = s * (1.0f / (HH * WW));
  }
}

// -------------------------------------------------------------------------
// Kernel 2: correlation volumes + fused per-block CMCAM FC prologue.
// A/B CHANGE vs previous round: plain float4 stores instead of
// __builtin_nontemporal_store. Everything else byte-identical.
// Volume core: block = (b, g, h2); 256 threads = dslot(4) x hl(2) x w4(32);
// register-ring over d; XOR-swizzled LDS (conflict-free by construction,
// hl-pair 2-way alias is free per m136).
// -------------------------------------------------------------------------
__global__ __launch_bounds__(256) void volume_kernel(
    const float* __restrict__ ref, const float* __restrict__ tgt,
    const float* __restrict__ gap /* [2][B][C] */,
    const float* __restrict__ w1, const float* __restrict__ b1,
    const float* __restrict__ w2, const float* __restrict__ b2,
    float* __restrict__ out) {
  __shared__ float Tl[2][CPG][WW];   // 8 KB, x-swizzled
  __shared__ float gsl[2 * CC];      // gap rows for this b: [img][c]
  __shared__ float hsl[2 * CR];      // FC1 out: [img][j]
  __shared__ float abw[2][CPG];      // masks -> alpha/beta

  int bid = blockIdx.x;              // b*(G*32) + g*32 + h2
  int b   = bid / (GG * 32);
  int rem = bid - b * (GG * 32);
  int g   = rem >> 5;
  int h2  = rem & 31;
  int tid = threadIdx.x;
  int dslot = tid >> 6;              // 0..3 (= wave id)
  int hl    = (tid >> 5) & 1;
  int w4    = tid & 31;
  int wq    = w4 << 2;
  int d0    = dslot * 12;
  int h     = h2 * 2 + hl;

  // ---- stage tgt rows -> LDS (swizzled); issue before FC so loads hide
  {
    int c_s = tid >> 5;
    int xq  = (tid & 31) << 2;
    int k   = (xq >> 5) & 3;         // swizzle key, constant over the quad
    size_t tb = ((size_t)((b * CC + g * CPG + c_s) * HH) + h2 * 2) * WW + xq;
    float4 v0 = *reinterpret_cast<const float4*>(tgt + tb);
    float4 v1 = *reinterpret_cast<const float4*>(tgt + tb + WW);
    float4 q0 = (k & 1) ? make_float4(v0.y, v0.x, v0.w, v0.z) : v0;
    q0 = (k & 2) ? make_float4(q0.z, q0.w, q0.x, q0.y) : q0;
    float4 q1 = (k & 1) ? make_float4(v1.y, v1.x, v1.w, v1.z) : v1;
    q1 = (k & 2) ? make_float4(q1.z, q1.w, q1.x, q1.y) : q1;
    *reinterpret_cast<float4*>(&Tl[0][c_s][xq]) = q0;
    *reinterpret_cast<float4*>(&Tl[1][c_s][xq]) = q1;
  }

  // ---- ref quads -> registers
  float rf[CPG][4];
  size_t rbase = ((size_t)((b * CC + g * CPG) * HH) + h) * WW + wq;
#pragma unroll
  for (int c = 0; c < CPG; ++c) {
    float4 rv = *reinterpret_cast<const float4*>(ref + rbase + (size_t)c * (HH * WW));
    rf[c][0] = rv.x; rf[c][1] = rv.y; rf[c][2] = rv.z; rf[c][3] = rv.w;
  }

  // ---- stage this b's gap rows (both images): 640 floats
  for (int i = tid; i < 2 * CC; i += 256) {
    int img = i >= CC;
    gsl[i] = gap[img * (BB * CC) + b * CC + (i - img * CC)];
  }
  __syncthreads();                   // gsl + Tl ready

  // ---- FC1: 40 dot-pairs of length 320; 80 threads = (j, quarter)
  if (tid < 80) {
    int j = tid >> 2, q = tid & 3;
    const float4* wrow = reinterpret_cast<const float4*>(w1 + j * CC) + q * 20;
    const float4* g0 = reinterpret_cast<const float4*>(gsl) + q * 20;
    const float4* g1 = reinterpret_cast<const float4*>(gsl + CC) + q * 20;
    float s0 = 0.f, s1 = 0.f;
#pragma unroll 5
    for (int c2 = 0; c2 < 20; ++c2) {
      float4 a = wrow[c2];
      float4 x0 = g0[c2], x1 = g1[c2];
      s0 += a.x * x0.x + a.y * x0.y + a.z * x0.z + a.w * x0.w;
      s1 += a.x * x1.x + a.y * x1.y + a.z * x1.z + a.w * x1.w;
    }
    s0 += __shfl_xor(s0, 1, 64); s1 += __shfl_xor(s1, 1, 64);
    s0 += __shfl_xor(s0, 2, 64); s1 += __shfl_xor(s1, 2, 64);
    if (q == 0) {
      float t0 = s0 + b1[j];
      float t1 = s1 + b1[j];
      hsl[j]      = t0 > 0.f ? t0 : 0.f;   // ReLU, img 0
      hsl[CR + j] = t1 > 0.f ? t1 : 0.f;   // ReLU, img 1
    }
  }
  __syncthreads();

  // ---- FC2 + sigmoid: only this group's 8 channels x 2 images
  if (tid < 16) {
    int img = tid >> 3, cl = tid & 7;
    int c = g * CPG + cl;
    float s = b2[c];
    const float* wrow = w2 + c * CR;
    const float* hr = hsl + img * CR;
#pragma unroll
    for (int j = 0; j < CR; ++j) s += wrow[j] * hr[j];
    abw[img][cl] = 1.f / (1.f + expf(-s));  // mask
  }
  __syncthreads();
  if (tid < CPG) {                   // masks -> fused alpha/beta (in place)
    float m0 = abw[0][tid], m1 = abw[1][tid];
    abw[0][tid] = m0 * m1 * 0.125f;
    abw[1][tid] = (1.f - m0) * (1.f - m1) * 0.125f;
  }
  __syncthreads();

  float al[CPG], be[CPG];
#pragma unroll
  for (int c = 0; c < CPG; ++c) {
    al[c] = abw[0][c];
    be[c] = abw[1][c];
  }

  // ---- ring prefill: slot r holds tap x = A + r
  const int A = wq - d0;
  float t[CPG][4];
#pragma unroll
  for (int r = 0; r < 4; ++r) {
    int x  = A + r;
    int xc = x < 0 ? 0 : x;
    int xs = xc ^ ((xc >> 5) & 3);
#pragma unroll
    for (int c = 0; c < CPG; ++c) {
      float v = Tl[hl][c][xs];
      t[c][r] = x < 0 ? 0.f : v;
    }
  }

  size_t o_hf = (((size_t)(b * 2 * GG + g) * MAXDISP + d0) * HH + h) * WW + wq;
  size_t o_ct = o_hf + (size_t)GG * MAXDISP * HH * WW;
#pragma unroll
  for (int i = 0; i < 12; ++i) {
    if (i > 0) {                     // slide window: new tap x = A - i
      int x  = A - i;
      int xc = x < 0 ? 0 : x;
      int xs = xc ^ ((xc >> 5) & 3);
      const int s = (16 - i) & 3;    // slot being replaced
#pragma unroll
      for (int c = 0; c < CPG; ++c) {
        float v = Tl[hl][c][xs];
        t[c][s] = x < 0 ? 0.f : v;
      }
    }
    float o0h = 0.f, o1h = 0.f, o2h = 0.f, o3h = 0.f;
    float o0c = 0.f, o1c = 0.f, o2c = 0.f, o3c = 0.f;
#pragma unroll
    for (int c = 0; c < CPG; ++c) {
      float p0 = rf[c][0] * t[c][(16 + 0 - i) & 3];
      float p1 = rf[c][1] * t[c][(16 + 1 - i) & 3];
      float p2 = rf[c][2] * t[c][(16 + 2 - i) & 3];
      float p3 = rf[c][3] * t[c][(16 + 3 - i) & 3];
      o0h += p0 * al[c]; o0c += p0 * be[c];
      o1h += p1 * al[c]; o1c += p1 * be[c];
      o2h += p2 * al[c]; o2c += p2 * be[c];
      o3h += p3 * al[c]; o3c += p3 * be[c];
    }
    fx4 vh = {o0h, o1h, o2h, o3h};
    fx4 vc = {o0c, o1c, o2c, o3c};
    *reinterpret_cast<fx4*>(out + o_hf) = vh;   // plain stores (A/B vs nt)
    *reinterpret_cast<fx4*>(out + o_ct) = vc;
    o_hf += HH * WW;
    o_ct += HH * WW;
  }
}

// -------------------------------------------------------------------------
extern "C" void kernel_launch(void* const* d_in, const int* in_sizes, int n_in,
                              void* d_out, int out_size, void* d_ws, size_t ws_size,
                              hipStream_t stream) {
  const float* ref = (const float*)d_in[0];
  const float* tgt = (const float*)d_in[1];
  const float* w1  = (const float*)d_in[2];
  const float* b1  = (const float*)d_in[3];
  const float* w2  = (const float*)d_in[4];
  const float* b2  = (const float*)d_in[5];
  float* out = (float*)d_out;
  float* gap = (float*)d_ws;       // 1280 floats

  gap_kernel<<<2 * BB * CC, 256, 0, stream>>>(ref, tgt, gap);
  volume_kernel<<<BB * GG * 32, 256, 0, stream>>>(ref, tgt, gap,
                                                  w1, b1, w2, b2, out);
}

// Round 9
// 65.689 us; speedup vs baseline: 1.0055x; 1.0055x over previous
//
#include <hip/hip_runtime.h>
#include <hip/hip_bf16.h>

#define BB 2
#define CC 320
#define HH 64
#define WW 128
#define MAXDISP 48
#define GG 40
#define CPG 8     // channels per group = C / G
#define CR 20     // C / R

typedef float fx4 __attribute__((ext_vector_type(4)));

// -------------------------------------------------------------------------
// Kernel 1: global average pool over H*W for each (img, b, c) row.
// 1280 blocks. Plain stores; visibility to the next kernel via the normal
// end-of-dispatch L2 flush (same-stream ordering) -- no atomics.
// -------------------------------------------------------------------------
__global__ __launch_bounds__(256) void gap_kernel(
    const float* __restrict__ ref, const float* __restrict__ tgt,
    float* __restrict__ gap /* [2][B][C] */) {
  int bid = blockIdx.x;            // 0 .. 1280
  int img = bid / (BB * CC);       // 0/1
  int rc  = bid - img * (BB * CC); // b*C + c
  const float* src = (img ? tgt : ref) + (size_t)rc * (HH * WW);
  const float4* v = reinterpret_cast<const float4*>(src);
  float acc = 0.f;
  for (int i = threadIdx.x; i < (HH * WW) / 4; i += 256) {
    float4 x = v[i];
    acc += (x.x + x.y) + (x.z + x.w);
  }
  for (int off = 32; off; off >>= 1) acc += __shfl_down(acc, off, 64);
  __shared__ float part[4];
  if ((threadIdx.x & 63) == 0) part[threadIdx.x >> 6] = acc;
  __syncthreads();
  if (threadIdx.x == 0) {
    float s = (part[0] + part[1]) + (part[2] + part[3]);
    gap[bid] = s * (1.0f / (HH * WW));
  }
}

// -------------------------------------------------------------------------
// Kernel 2: correlation volumes + fused per-block CMCAM FC prologue.
// A/B CHANGE vs R7 (65.6 us): XCD-aware bijective block swizzle so each XCD
// owns contiguous (b,g) plane-sets -- all 32 h2-blocks of a plane-set run on
// ONE XCD, so their interleaved 1 KB chunks merge into contiguous 32 KB
// d-planes in that XCD's L2 (write locality). nwg = 2560 = 8*320 exactly.
// Volume core unchanged: block = (b, g, h2); 256 threads = dslot(4) x hl(2)
// x w4(32); register-ring over d; XOR-swizzled LDS; float4 nt stores.
// -------------------------------------------------------------------------
__global__ __launch_bounds__(256) void volume_kernel(
    const float* __restrict__ ref, const float* __restrict__ tgt,
    const float* __restrict__ gap /* [2][B][C] */,
    const float* __restrict__ w1, const float* __restrict__ b1,
    const float* __restrict__ w2, const float* __restrict__ b2,
    float* __restrict__ out) {
  __shared__ float Tl[2][CPG][WW];   // 8 KB, x-swizzled
  __shared__ float gsl[2 * CC];      // gap rows for this b: [img][c]
  __shared__ float hsl[2 * CR];      // FC1 out: [img][j]
  __shared__ float abw[2][CPG];      // masks -> alpha/beta

  // XCD-aware swizzle: work newbid runs on XCD (blockIdx.x & 7); each XCD
  // gets a contiguous range of 320 work items = 10 full (b,g) plane-sets.
  int bid = (blockIdx.x & 7) * 320 + (blockIdx.x >> 3);
  int b   = bid / (GG * 32);
  int rem = bid - b * (GG * 32);
  int g   = rem >> 5;
  int h2  = rem & 31;
  int tid = threadIdx.x;
  int dslot = tid >> 6;              // 0..3 (= wave id)
  int hl    = (tid >> 5) & 1;
  int w4    = tid & 31;
  int wq    = w4 << 2;
  int d0    = dslot * 12;
  int h     = h2 * 2 + hl;

  // ---- stage tgt rows -> LDS (swizzled); issue before FC so loads hide
  {
    int c_s = tid >> 5;
    int xq  = (tid & 31) << 2;
    int k   = (xq >> 5) & 3;         // swizzle key, constant over the quad
    size_t tb = ((size_t)((b * CC + g * CPG + c_s) * HH) + h2 * 2) * WW + xq;
    float4 v0 = *reinterpret_cast<const float4*>(tgt + tb);
    float4 v1 = *reinterpret_cast<const float4*>(tgt + tb + WW);
    float4 q0 = (k & 1) ? make_float4(v0.y, v0.x, v0.w, v0.z) : v0;
    q0 = (k & 2) ? make_float4(q0.z, q0.w, q0.x, q0.y) : q0;
    float4 q1 = (k & 1) ? make_float4(v1.y, v1.x, v1.w, v1.z) : v1;
    q1 = (k & 2) ? make_float4(q1.z, q1.w, q1.x, q1.y) : q1;
    *reinterpret_cast<float4*>(&Tl[0][c_s][xq]) = q0;
    *reinterpret_cast<float4*>(&Tl[1][c_s][xq]) = q1;
  }

  // ---- ref quads -> registers
  float rf[CPG][4];
  size_t rbase = ((size_t)((b * CC + g * CPG) * HH) + h) * WW + wq;
#pragma unroll
  for (int c = 0; c < CPG; ++c) {
    float4 rv = *reinterpret_cast<const float4*>(ref + rbase + (size_t)c * (HH * WW));
    rf[c][0] = rv.x; rf[c][1] = rv.y; rf[c][2] = rv.z; rf[c][3] = rv.w;
  }

  // ---- stage this b's gap rows (both images): 640 floats
  for (int i = tid; i < 2 * CC; i += 256) {
    int img = i >= CC;
    gsl[i] = gap[img * (BB * CC) + b * CC + (i - img * CC)];
  }
  __syncthreads();                   // gsl + Tl ready

  // ---- FC1: 40 dot-pairs of length 320; 80 threads = (j, quarter)
  if (tid < 80) {
    int j = tid >> 2, q = tid & 3;
    const float4* wrow = reinterpret_cast<const float4*>(w1 + j * CC) + q * 20;
    const float4* g0 = reinterpret_cast<const float4*>(gsl) + q * 20;
    const float4* g1 = reinterpret_cast<const float4*>(gsl + CC) + q * 20;
    float s0 = 0.f, s1 = 0.f;
#pragma unroll 5
    for (int c2 = 0; c2 < 20; ++c2) {
      float4 a = wrow[c2];
      float4 x0 = g0[c2], x1 = g1[c2];
      s0 += a.x * x0.x + a.y * x0.y + a.z * x0.z + a.w * x0.w;
      s1 += a.x * x1.x + a.y * x1.y + a.z * x1.z + a.w * x1.w;
    }
    s0 += __shfl_xor(s0, 1, 64); s1 += __shfl_xor(s1, 1, 64);
    s0 += __shfl_xor(s0, 2, 64); s1 += __shfl_xor(s1, 2, 64);
    if (q == 0) {
      float t0 = s0 + b1[j];
      float t1 = s1 + b1[j];
      hsl[j]      = t0 > 0.f ? t0 : 0.f;   // ReLU, img 0
      hsl[CR + j] = t1 > 0.f ? t1 : 0.f;   // ReLU, img 1
    }
  }
  __syncthreads();

  // ---- FC2 + sigmoid: only this group's 8 channels x 2 images
  if (tid < 16) {
    int img = tid >> 3, cl = tid & 7;
    int c = g * CPG + cl;
    float s = b2[c];
    const float* wrow = w2 + c * CR;
    const float* hr = hsl + img * CR;
#pragma unroll
    for (int j = 0; j < CR; ++j) s += wrow[j] * hr[j];
    abw[img][cl] = 1.f / (1.f + expf(-s));  // mask
  }
  __syncthreads();
  if (tid < CPG) {                   // masks -> fused alpha/beta (in place)
    float m0 = abw[0][tid], m1 = abw[1][tid];
    abw[0][tid] = m0 * m1 * 0.125f;
    abw[1][tid] = (1.f - m0) * (1.f - m1) * 0.125f;
  }
  __syncthreads();

  float al[CPG], be[CPG];
#pragma unroll
  for (int c = 0; c < CPG; ++c) {
    al[c] = abw[0][c];
    be[c] = abw[1][c];
  }

  // ---- ring prefill: slot r holds tap x = A + r
  const int A = wq - d0;
  float t[CPG][4];
#pragma unroll
  for (int r = 0; r < 4; ++r) {
    int x  = A + r;
    int xc = x < 0 ? 0 : x;
    int xs = xc ^ ((xc >> 5) & 3);
#pragma unroll
    for (int c = 0; c < CPG; ++c) {
      float v = Tl[hl][c][xs];
      t[c][r] = x < 0 ? 0.f : v;
    }
  }

  size_t o_hf = (((size_t)(b * 2 * GG + g) * MAXDISP + d0) * HH + h) * WW + wq;
  size_t o_ct = o_hf + (size_t)GG * MAXDISP * HH * WW;
#pragma unroll
  for (int i = 0; i < 12; ++i) {
    if (i > 0) {                     // slide window: new tap x = A - i
      int x  = A - i;
      int xc = x < 0 ? 0 : x;
      int xs = xc ^ ((xc >> 5) & 3);
      const int s = (16 - i) & 3;    // slot being replaced
#pragma unroll
      for (int c = 0; c < CPG; ++c) {
        float v = Tl[hl][c][xs];
        t[c][s] = x < 0 ? 0.f : v;
      }
    }
    float o0h = 0.f, o1h = 0.f, o2h = 0.f, o3h = 0.f;
    float o0c = 0.f, o1c = 0.f, o2c = 0.f, o3c = 0.f;
#pragma unroll
    for (int c = 0; c < CPG; ++c) {
      float p0 = rf[c][0] * t[c][(16 + 0 - i) & 3];
      float p1 = rf[c][1] * t[c][(16 + 1 - i) & 3];
      float p2 = rf[c][2] * t[c][(16 + 2 - i) & 3];
      float p3 = rf[c][3] * t[c][(16 + 3 - i) & 3];
      o0h += p0 * al[c]; o0c += p0 * be[c];
      o1h += p1 * al[c]; o1c += p1 * be[c];
      o2h += p2 * al[c]; o2c += p2 * be[c];
      o3h += p3 * al[c]; o3c += p3 * be[c];
    }
    fx4 vh = {o0h, o1h, o2h, o3h};
    fx4 vc = {o0c, o1c, o2c, o3c};
    __builtin_nontemporal_store(vh, reinterpret_cast<fx4*>(out + o_hf));
    __builtin_nontemporal_store(vc, reinterpret_cast<fx4*>(out + o_ct));
    o_hf += HH * WW;
    o_ct += HH * WW;
  }
}

// -------------------------------------------------------------------------
extern "C" void kernel_launch(void* const* d_in, const int* in_sizes, int n_in,
                              void* d_out, int out_size, void* d_ws, size_t ws_size,
                              hipStream_t stream) {
  const float* ref = (const float*)d_in[0];
  const float* tgt = (const float*)d_in[1];
  const float* w1  = (const float*)d_in[2];
  const float* b1  = (const float*)d_in[3];
  const float* w2  = (const float*)d_in[4];
  const float* b2  = (const float*)d_in[5];
  float* out = (float*)d_out;
  float* gap = (float*)d_ws;       // 1280 floats

  gap_kernel<<<2 * BB * CC, 256, 0, stream>>>(ref, tgt, gap);
  volume_kernel<<<BB * GG * 32, 256, 0, stream>>>(ref, tgt, gap,
                                                  w1, b1, w2, b2, out);
}

// Round 10
// 61.877 us; speedup vs baseline: 1.0675x; 1.0616x over previous
//
#include <hip/hip_runtime.h>
#include <hip/hip_bf16.h>

#define BB 2
#define CC 320
#define HH 64
#define WW 128
#define MAXDISP 48
#define GG 40
#define CPG 8     // channels per group = C / G
#define CR 20     // C / R
#define HT 4      // h-rows per volume block tile

typedef float fx4 __attribute__((ext_vector_type(4)));

// -------------------------------------------------------------------------
// Kernel 1: global average pool over H*W for each (img, b, c) row.
// 1280 blocks. Plain stores; cross-kernel visibility via end-of-dispatch
// flush (same-stream ordering).
// -------------------------------------------------------------------------
__global__ __launch_bounds__(256) void gap_kernel(
    const float* __restrict__ ref, const float* __restrict__ tgt,
    float* __restrict__ gap /* [2][B][C] */) {
  int bid = blockIdx.x;            // 0 .. 1280
  int img = bid / (BB * CC);       // 0/1
  int rc  = bid - img * (BB * CC); // b*C + c
  const float* src = (img ? tgt : ref) + (size_t)rc * (HH * WW);
  const float4* v = reinterpret_cast<const float4*>(src);
  float acc = 0.f;
  for (int i = threadIdx.x; i < (HH * WW) / 4; i += 256) {
    float4 x = v[i];
    acc += (x.x + x.y) + (x.z + x.w);
  }
  for (int off = 32; off; off >>= 1) acc += __shfl_down(acc, off, 64);
  __shared__ float part[4];
  if ((threadIdx.x & 63) == 0) part[threadIdx.x >> 6] = acc;
  __syncthreads();
  if (threadIdx.x == 0) {
    float s = (part[0] + part[1]) + (part[2] + part[3]);
    gap[bid] = s * (1.0f / (HH * WW));
  }
}

// -------------------------------------------------------------------------
// Kernel 2: correlation volumes + fused per-block CMCAM FC prologue.
// CHANGE vs 65.6 us rounds: h4 TILE. Block = (b, g, h4) owns 4 h-rows
// (1280 blocks = exactly 5/CU): tgt tile staged ONCE into 16 KB LDS, FC +
// gap staging + all barriers paid once per 2 h-pairs; hp-loop then runs
// barrier-free. Amortizes the per-block prologue that R4~R7 equality
// exposed as a real cost. Store pattern per step unchanged (fx4 nt).
// -------------------------------------------------------------------------
__global__ __launch_bounds__(256) void volume_kernel(
    const float* __restrict__ ref, const float* __restrict__ tgt,
    const float* __restrict__ gap /* [2][B][C] */,
    const float* __restrict__ w1, const float* __restrict__ b1,
    const float* __restrict__ w2, const float* __restrict__ b2,
    float* __restrict__ out) {
  __shared__ float Tl[HT][CPG][WW];  // 16 KB, x-swizzled
  __shared__ float gsl[2 * CC];      // gap rows for this b: [img][c]
  __shared__ float hsl[2 * CR];      // FC1 out: [img][j]
  __shared__ float abw[2][CPG];      // masks -> alpha/beta

  int bid = blockIdx.x;              // b*(G*16) + g*16 + h4
  int b   = bid / (GG * 16);
  int rem = bid - b * (GG * 16);
  int g   = rem >> 4;
  int h4  = rem & 15;
  int tid = threadIdx.x;
  int dslot = tid >> 6;              // 0..3 (= wave id)
  int hl    = (tid >> 5) & 1;
  int w4    = tid & 31;
  int wq    = w4 << 2;
  int d0    = dslot * 12;

  // ---- stage tgt tile -> LDS (swizzled): 4h x 8c x 128w = 1024 quads,
  // 4 per thread, coalesced (consecutive tid = consecutive xq within (h,c)).
#pragma unroll
  for (int p = 0; p < 4; ++p) {
    int q    = p * 256 + tid;
    int hrow = q >> 8;
    int c    = (q >> 5) & 7;
    int x4   = q & 31;
    int xq   = x4 << 2;
    int k    = (x4 >> 3) & 3;        // swizzle key, constant over the quad
    size_t tb = ((size_t)((b * CC + g * CPG + c) * HH) + h4 * HT + hrow) * WW + xq;
    float4 v0 = *reinterpret_cast<const float4*>(tgt + tb);
    float4 q0 = (k & 1) ? make_float4(v0.y, v0.x, v0.w, v0.z) : v0;
    q0 = (k & 2) ? make_float4(q0.z, q0.w, q0.x, q0.y) : q0;
    *reinterpret_cast<float4*>(&Tl[hrow][c][xq]) = q0;
  }

  // ---- stage this b's gap rows (both images): 640 floats
  for (int i = tid; i < 2 * CC; i += 256) {
    int img = i >= CC;
    gsl[i] = gap[img * (BB * CC) + b * CC + (i - img * CC)];
  }
  __syncthreads();                   // gsl + Tl ready

  // ---- FC1: 40 dot-pairs of length 320; 80 threads = (j, quarter)
  if (tid < 80) {
    int j = tid >> 2, q = tid & 3;
    const float4* wrow = reinterpret_cast<const float4*>(w1 + j * CC) + q * 20;
    const float4* g0 = reinterpret_cast<const float4*>(gsl) + q * 20;
    const float4* g1 = reinterpret_cast<const float4*>(gsl + CC) + q * 20;
    float s0 = 0.f, s1 = 0.f;
#pragma unroll 5
    for (int c2 = 0; c2 < 20; ++c2) {
      float4 a = wrow[c2];
      float4 x0 = g0[c2], x1 = g1[c2];
      s0 += a.x * x0.x + a.y * x0.y + a.z * x0.z + a.w * x0.w;
      s1 += a.x * x1.x + a.y * x1.y + a.z * x1.z + a.w * x1.w;
    }
    s0 += __shfl_xor(s0, 1, 64); s1 += __shfl_xor(s1, 1, 64);
    s0 += __shfl_xor(s0, 2, 64); s1 += __shfl_xor(s1, 2, 64);
    if (q == 0) {
      float t0 = s0 + b1[j];
      float t1 = s1 + b1[j];
      hsl[j]      = t0 > 0.f ? t0 : 0.f;   // ReLU, img 0
      hsl[CR + j] = t1 > 0.f ? t1 : 0.f;   // ReLU, img 1
    }
  }
  __syncthreads();

  // ---- FC2 + sigmoid: only this group's 8 channels x 2 images
  if (tid < 16) {
    int img = tid >> 3, cl = tid & 7;
    int c = g * CPG + cl;
    float s = b2[c];
    const float* wrow = w2 + c * CR;
    const float* hr = hsl + img * CR;
#pragma unroll
    for (int j = 0; j < CR; ++j) s += wrow[j] * hr[j];
    abw[img][cl] = 1.f / (1.f + expf(-s));  // mask
  }
  __syncthreads();
  if (tid < CPG) {                   // masks -> fused alpha/beta (in place)
    float m0 = abw[0][tid], m1 = abw[1][tid];
    abw[0][tid] = m0 * m1 * 0.125f;
    abw[1][tid] = (1.f - m0) * (1.f - m1) * 0.125f;
  }
  __syncthreads();

  float al[CPG], be[CPG];
#pragma unroll
  for (int c = 0; c < CPG; ++c) {
    al[c] = abw[0][c];
    be[c] = abw[1][c];
  }

  // ---- hp-loop over the tile's two h-pairs; no barriers inside (Tl is
  // read-only from here on).
  const int A = wq - d0;
  for (int hp = 0; hp < HT / 2; ++hp) {
    int h_local = hp * 2 + hl;
    int h = h4 * HT + h_local;

    // ref quads -> registers for this h
    float rf[CPG][4];
    size_t rbase = ((size_t)((b * CC + g * CPG) * HH) + h) * WW + wq;
#pragma unroll
    for (int c = 0; c < CPG; ++c) {
      float4 rv = *reinterpret_cast<const float4*>(ref + rbase + (size_t)c * (HH * WW));
      rf[c][0] = rv.x; rf[c][1] = rv.y; rf[c][2] = rv.z; rf[c][3] = rv.w;
    }

    // ring prefill: slot r holds tap x = A + r
    float t[CPG][4];
#pragma unroll
    for (int r = 0; r < 4; ++r) {
      int x  = A + r;
      int xc = x < 0 ? 0 : x;
      int xs = xc ^ ((xc >> 5) & 3);
#pragma unroll
      for (int c = 0; c < CPG; ++c) {
        float v = Tl[h_local][c][xs];
        t[c][r] = x < 0 ? 0.f : v;
      }
    }

    size_t o_hf = (((size_t)(b * 2 * GG + g) * MAXDISP + d0) * HH + h) * WW + wq;
    size_t o_ct = o_hf + (size_t)GG * MAXDISP * HH * WW;
#pragma unroll
    for (int i = 0; i < 12; ++i) {
      if (i > 0) {                   // slide window: new tap x = A - i
        int x  = A - i;
        int xc = x < 0 ? 0 : x;
        int xs = xc ^ ((xc >> 5) & 3);
        const int s = (16 - i) & 3;  // slot being replaced
#pragma unroll
        for (int c = 0; c < CPG; ++c) {
          float v = Tl[h_local][c][xs];
          t[c][s] = x < 0 ? 0.f : v;
        }
      }
      float o0h = 0.f, o1h = 0.f, o2h = 0.f, o3h = 0.f;
      float o0c = 0.f, o1c = 0.f, o2c = 0.f, o3c = 0.f;
#pragma unroll
      for (int c = 0; c < CPG; ++c) {
        float p0 = rf[c][0] * t[c][(16 + 0 - i) & 3];
        float p1 = rf[c][1] * t[c][(16 + 1 - i) & 3];
        float p2 = rf[c][2] * t[c][(16 + 2 - i) & 3];
        float p3 = rf[c][3] * t[c][(16 + 3 - i) & 3];
        o0h += p0 * al[c]; o0c += p0 * be[c];
        o1h += p1 * al[c]; o1c += p1 * be[c];
        o2h += p2 * al[c]; o2c += p2 * be[c];
        o3h += p3 * al[c]; o3c += p3 * be[c];
      }
      fx4 vh = {o0h, o1h, o2h, o3h};
      fx4 vc = {o0c, o1c, o2c, o3c};
      __builtin_nontemporal_store(vh, reinterpret_cast<fx4*>(out + o_hf));
      __builtin_nontemporal_store(vc, reinterpret_cast<fx4*>(out + o_ct));
      o_hf += HH * WW;
      o_ct += HH * WW;
    }
  }
}

// -------------------------------------------------------------------------
extern "C" void kernel_launch(void* const* d_in, const int* in_sizes, int n_in,
                              void* d_out, int out_size, void* d_ws, size_t ws_size,
                              hipStream_t stream) {
  const float* ref = (const float*)d_in[0];
  const float* tgt = (const float*)d_in[1];
  const float* w1  = (const float*)d_in[2];
  const float* b1  = (const float*)d_in[3];
  const float* w2  = (const float*)d_in[4];
  const float* b2  = (const float*)d_in[5];
  float* out = (float*)d_out;
  float* gap = (float*)d_ws;       // 1280 floats

  gap_kernel<<<2 * BB * CC, 256, 0, stream>>>(ref, tgt, gap);
  volume_kernel<<<BB * GG * 16, 256, 0, stream>>>(ref, tgt, gap,
                                                  w1, b1, w2, b2, out);
}